// Round 17
// baseline (228.040 us; speedup 1.0000x reference)
//
#include <hip/hip_runtime.h>

#define BATCH 256
#define L 1024
#define C 16
#define POOL 512
#define PCOLS 5632
#define FDIM 90112        // C*PCOLS
#define H1 128
#define H2 64

#define KS 64             // split-K factor for mfma GEMM
#define KCHUNK (FDIM / KS)   // 1408

#define HPOS 512                   // positions per tree08 block
#define HBUF (8192 + 256)          // 512*16 + skew pad (floats)

typedef float f32x4 __attribute__((ext_vector_type(4)));
typedef short bf16x8 __attribute__((ext_vector_type(8)));

__device__ __forceinline__ int skew(int i) { return i + (i >> 5); }

__device__ __forceinline__ unsigned short f2b(float f) {
    union { float f; unsigned int u; } v; v.f = f;
    unsigned int r = (v.u + 0x7FFFu + ((v.u >> 16) & 1u)) >> 16;   // RNE
    return (unsigned short)r;
}

// ---------------- Kernel 1a: tree levels leaf..8, half-batch blocks ----------------
// grid = BATCH*2; block (b, h) owns positions [h*512, h*512+512) -- independent
// through level 8 (nodes nest in 512). Single 33.8KB LDS buffer -> 4 blocks/CU.
__launch_bounds__(256, 4)
__global__ void tree08(const float* __restrict__ x,
                       const float* __restrict__ leaf_w,
                       const float* __restrict__ leaf_b,
                       const float* __restrict__ conv_w,
                       const float* __restrict__ conv_b,
                       const float* __restrict__ bn_gamma,
                       const float* __restrict__ bn_beta,
                       const float* __restrict__ node_w,
                       unsigned short* __restrict__ pooledb,
                       float* __restrict__ glvl8) {
    __shared__ float buf[HBUF];
    __shared__ float sc[C], bt[C];

    const int bid = blockIdx.x;
    const int b   = bid >> 1;
    const int h   = bid & 1;
    const int tid = threadIdx.x;          // 0..255 = local position pair

    if (tid < 16) {
        float s = bn_gamma[tid] / sqrtf(1.0f + 1e-5f);
        sc[tid] = s;
        bt[tid] = conv_b[tid] * s + bn_beta[tid];
    }

    const int g0 = h * HPOS + 2 * tid;    // global position of first owned pos

    // ---- leaf stage ----
    {
        const float2 xv  = *(const float2*)(x + b * L + g0);
        const float2 nw2 = *(const float2*)(node_w + g0);
        const float4* lwa = (const float4*)(leaf_w + 16 * g0);
        const float4* lba = (const float4*)(leaf_b + 16 * g0);
#pragma unroll 1
        for (int q = 0; q < 4; ++q) {
            float4 w0 = lwa[q],     bb0 = lba[q];
            float4 w1 = lwa[q + 4], bb1 = lba[q + 4];
            float v0[4], v1[4];
            v0[0] = (xv.x * w0.x + bb0.x) * nw2.x;  v1[0] = (xv.y * w1.x + bb1.x) * nw2.y;
            v0[1] = (xv.x * w0.y + bb0.y) * nw2.x;  v1[1] = (xv.y * w1.y + bb1.y) * nw2.y;
            v0[2] = (xv.x * w0.z + bb0.z) * nw2.x;  v1[2] = (xv.y * w1.z + bb1.z) * nw2.y;
            v0[3] = (xv.x * w0.w + bb0.w) * nw2.x;  v1[3] = (xv.y * w1.w + bb1.w) * nw2.y;
#pragma unroll
            for (int j = 0; j < 4; ++j) {
                int c = 4 * q + j;
                buf[skew((2 * tid) * C + c)]     = v0[j];
                buf[skew((2 * tid + 1) * C + c)] = v1[j];
                pooledb[b * FDIM + c * PCOLS + h * 256 + tid] = f2b(fmaxf(v0[j], v1[j]));
            }
        }
        __syncthreads();
    }

    // ---- levels 0..8, in-place, 2 barriers each ----
    int noff = L;
    for (int d = 0; d < 9; ++d) {
        const int Lk = 1 << d;
        const int L2 = Lk << 1;
        const int n2 = tid >> d;              // local pair-node index
        const int tp = tid & (Lk - 1);
        const int t0 = tp << 1;

        int adr[4];
        const bool ok0 = (t0 > 0);
        const bool ok3 = (t0 + 2 < L2);
#pragma unroll
        for (int r = 0; r < 4; ++r) {
            int tt = t0 - 1 + r;
            int ttc = tt < 0 ? 0 : (tt > L2 - 1 ? L2 - 1 : tt);
            int node = 2 * n2 + (ttc >= Lk ? 1 : 0);
            adr[r] = node * (C * Lk) + (ttc & (Lk - 1));
        }

        const float nwv = node_w[noff + h * (256 >> d) + n2];
        const int ob = n2 * (C * L2) + t0;
        const int pb = b * FDIM + (d + 1) * POOL + h * 256 + tid;

        // READ phase (all 16 co, ci chunked 4x4 with unroll 1 -> no hoist-spill)
        float acc0[C], acc1[C];
#pragma unroll
        for (int co = 0; co < C; ++co) { acc0[co] = 0.f; acc1[co] = 0.f; }

#pragma unroll 1
        for (int cic = 0; cic < 4; ++cic) {
#pragma unroll
            for (int ci4 = 0; ci4 < 4; ++ci4) {
                const int ci = cic * 4 + ci4;
                const int o = ci * Lk;
                float vm1 = ok0 ? buf[skew(adr[0] + o)] : 0.f;
                float v0  = buf[skew(adr[1] + o)];
                float v1  = buf[skew(adr[2] + o)];
                float v2  = ok3 ? buf[skew(adr[3] + o)] : 0.f;
#pragma unroll
                for (int co = 0; co < C; ++co) {
                    const float* wp = conv_w + ((co * C) + ci) * 3;
                    const float wx = wp[0], wy = wp[1], wz = wp[2];
                    acc0[co] = fmaf(wx, vm1, fmaf(wy, v0, fmaf(wz, v1, acc0[co])));
                    acc1[co] = fmaf(wx, v0,  fmaf(wy, v1, fmaf(wz, v2, acc1[co])));
                }
            }
        }

        __syncthreads();   // reads complete

        // WRITE phase
        if (d < 8) {
#pragma unroll
            for (int co = 0; co < C; ++co) {
                float z0 = fmaxf(fmaf(sc[co], acc0[co], bt[co]), 0.f) * nwv;
                float z1 = fmaxf(fmaf(sc[co], acc1[co], bt[co]), 0.f) * nwv;
                buf[skew(ob + co * L2)]     = z0;
                buf[skew(ob + co * L2 + 1)] = z1;
                pooledb[pb + co * PCOLS] = f2b(fmaxf(z0, z1));
            }
        } else {
            // level-8 output -> global [b][pos][ch] for the level-9 kernel
            float* gp = glvl8 + ((long)b * L + g0) * C;
#pragma unroll
            for (int co = 0; co < C; ++co) {
                float z0 = fmaxf(fmaf(sc[co], acc0[co], bt[co]), 0.f) * nwv;
                float z1 = fmaxf(fmaf(sc[co], acc1[co], bt[co]), 0.f) * nwv;
                gp[co]     = z0;
                gp[C + co] = z1;
                pooledb[pb + co * PCOLS] = f2b(fmaxf(z0, z1));
            }
        }

        __syncthreads();
        noff += (512 >> d);    // global node count at level d
    }
}

// ---------------- Kernel 1c: tree level 9 (full 1024-node) + last pooled row ----
// grid = BATCH x 512 thr; taps read from L3-resident glvl8, no LDS.
__launch_bounds__(512, 2)
__global__ void tree9(const float* __restrict__ glvl8,
                      const float* __restrict__ conv_w,
                      const float* __restrict__ conv_b,
                      const float* __restrict__ bn_gamma,
                      const float* __restrict__ bn_beta,
                      const float* __restrict__ node_w,
                      unsigned short* __restrict__ pooledb) {
    const int b   = blockIdx.x;
    const int tid = threadIdx.x;          // out position pair (2t, 2t+1)

    const float nwv = node_w[2046];       // single level-9 node
    const bool okm = (tid > 0);
    const bool okp = (tid < 511);

    const float* base = glvl8 + (long)b * L * C;
    const float* rm1 = base + (2 * tid - 1) * C;   // guarded by okm
    const float* r0  = base + (2 * tid) * C;
    const float* r1  = base + (2 * tid + 1) * C;
    const float* r2  = base + (2 * tid + 2) * C;   // guarded by okp

    float acc0[C], acc1[C];
#pragma unroll
    for (int co = 0; co < C; ++co) { acc0[co] = 0.f; acc1[co] = 0.f; }

#pragma unroll 1
    for (int cic = 0; cic < 4; ++cic) {
        const int c0 = cic * 4;
        f32x4 vm1 = okm ? *(const f32x4*)(rm1 + c0) : (f32x4){0.f, 0.f, 0.f, 0.f};
        f32x4 v0  = *(const f32x4*)(r0 + c0);
        f32x4 v1  = *(const f32x4*)(r1 + c0);
        f32x4 v2  = okp ? *(const f32x4*)(r2 + c0) : (f32x4){0.f, 0.f, 0.f, 0.f};
#pragma unroll
        for (int ci4 = 0; ci4 < 4; ++ci4) {
            const int ci = c0 + ci4;
            const float a = vm1[ci4], e = v0[ci4], f = v1[ci4], g = v2[ci4];
#pragma unroll
            for (int co = 0; co < C; ++co) {
                const float* wp = conv_w + ((co * C) + ci) * 3;
                acc0[co] = fmaf(wp[0], a, fmaf(wp[1], e, fmaf(wp[2], f, acc0[co])));
                acc1[co] = fmaf(wp[0], e, fmaf(wp[1], f, fmaf(wp[2], g, acc1[co])));
            }
        }
    }

    const int pb = b * FDIM + 10 * POOL + tid;
#pragma unroll
    for (int co = 0; co < C; ++co) {
        float s = bn_gamma[co] / sqrtf(1.0f + 1e-5f);
        float bv = conv_b[co] * s + bn_beta[co];
        float z0 = fmaxf(fmaf(s, acc0[co], bv), 0.f) * nwv;
        float z1 = fmaxf(fmaf(s, acc1[co], bv), 0.f) * nwv;
        pooledb[pb + co * PCOLS] = f2b(fmaxf(z0, z1));
    }
}

// ---------------- Kernel 1b: fc1_w f32 -> bf16 ----------------
__launch_bounds__(256)
__global__ void w1_convert(const float* __restrict__ w1,
                           unsigned short* __restrict__ w1b) {
    const int n4 = (H1 * FDIM) >> 2;
    for (int i = blockIdx.x * blockDim.x + threadIdx.x; i < n4;
         i += gridDim.x * blockDim.x) {
        float4 v = *(const float4*)(w1 + 4 * i);
        ushort4 o;
        o.x = f2b(v.x); o.y = f2b(v.y); o.z = f2b(v.z); o.w = f2b(v.w);
        *(ushort4*)(w1b + 4 * i) = o;
    }
}

// ---------------- Kernel 2: fc1 via MFMA bf16, split-K, no LDS ----------------
__launch_bounds__(256, 2)
__global__ void fc1_mfma(const unsigned short* __restrict__ pooledb,
                         const unsigned short* __restrict__ w1b,
                         float* __restrict__ partial) {
    const int bid = blockIdx.x;
    const int ks  = bid & (KS - 1);
    const int g   = bid >> 6;
    const int bm  = g >> 1;
    const int bn  = g & 1;

    const int tid  = threadIdx.x;
    const int wv   = tid >> 6;
    const int lane = tid & 63;

    const int m0 = bm * 64 + wv * 16;
    const int n0 = bn * 64;
    const int kb = ks * KCHUNK;

    const int lrow = lane & 15;
    const int lk   = (lane >> 4) * 8;

    const unsigned short* ap  = pooledb + (long)(m0 + lrow) * FDIM + kb + lk;
    const unsigned short* bp0 = w1b + (long)(n0 + lrow) * FDIM + kb + lk;

    f32x4 acc0 = {0.f, 0.f, 0.f, 0.f};
    f32x4 acc1 = {0.f, 0.f, 0.f, 0.f};
    f32x4 acc2 = {0.f, 0.f, 0.f, 0.f};
    f32x4 acc3 = {0.f, 0.f, 0.f, 0.f};

#pragma unroll 2
    for (int kk = 0; kk < KCHUNK; kk += 32) {
        bf16x8 a  = *(const bf16x8*)(ap + kk);
        bf16x8 b0 = *(const bf16x8*)(bp0 + kk);
        bf16x8 b1 = *(const bf16x8*)(bp0 + 16 * FDIM + kk);
        bf16x8 b2 = *(const bf16x8*)(bp0 + 32 * FDIM + kk);
        bf16x8 b3 = *(const bf16x8*)(bp0 + 48 * FDIM + kk);
        acc0 = __builtin_amdgcn_mfma_f32_16x16x32_bf16(a, b0, acc0, 0, 0, 0);
        acc1 = __builtin_amdgcn_mfma_f32_16x16x32_bf16(a, b1, acc1, 0, 0, 0);
        acc2 = __builtin_amdgcn_mfma_f32_16x16x32_bf16(a, b2, acc2, 0, 0, 0);
        acc3 = __builtin_amdgcn_mfma_f32_16x16x32_bf16(a, b3, acc3, 0, 0, 0);
    }

    const int crow = m0 + (lane >> 4) * 4;
    const int ccol = n0 + (lane & 15);
    float* pp = partial + (long)ks * (BATCH * H1) + (long)crow * H1 + ccol;
#pragma unroll
    for (int r = 0; r < 4; ++r) {
        pp[(long)r * H1]      = acc0[r];
        pp[(long)r * H1 + 16] = acc1[r];
        pp[(long)r * H1 + 32] = acc2[r];
        pp[(long)r * H1 + 48] = acc3[r];
    }
}

// ---------------- Kernel 3: reduce partials + fc1 bias/relu + fc2 + fc3 ----------
__launch_bounds__(128)
__global__ void fc_tail(const float* __restrict__ partial,
                        const float* __restrict__ fc1_b,
                        const float* __restrict__ w2,
                        const float* __restrict__ b2,
                        const float* __restrict__ w3,
                        const float* __restrict__ b3,
                        float* __restrict__ out, int nkt) {
    __shared__ float h1_s[H1];
    __shared__ float w2_s[H2 * 129];

    const int b = blockIdx.x;
    const int t = threadIdx.x;

    float s = 0.f;
    for (int kt = 0; kt < nkt; ++kt)
        s += partial[(long)kt * (BATCH * H1) + b * H1 + t];
    h1_s[t] = fmaxf(s + fc1_b[t], 0.f);

    for (int i = t; i < H2 * H1; i += 128) {
        int j = i >> 7, k = i & 127;
        w2_s[j * 129 + k] = w2[i];
    }
    __syncthreads();

    if (t < 64) {
        float a2 = 0.f;
#pragma unroll 8
        for (int k = 0; k < H1; ++k) a2 = fmaf(h1_s[k], w2_s[t * 129 + k], a2);
        float h2 = fmaxf(a2 + b2[t], 0.f);
        float r = h2 * w3[t];
#pragma unroll
        for (int off = 32; off > 0; off >>= 1) r += __shfl_down(r, off);
        if (t == 0) out[b] = r + b3[0];
    }
}

extern "C" void kernel_launch(void* const* d_in, const int* in_sizes, int n_in,
                              void* d_out, int out_size, void* d_ws, size_t ws_size,
                              hipStream_t stream) {
    const float* x        = (const float*)d_in[0];
    const float* leaf_w   = (const float*)d_in[1];
    const float* leaf_b   = (const float*)d_in[2];
    const float* conv_w   = (const float*)d_in[3];
    const float* conv_b   = (const float*)d_in[4];
    const float* bn_gamma = (const float*)d_in[5];
    const float* bn_beta  = (const float*)d_in[6];
    const float* node_w   = (const float*)d_in[7];
    const float* fc1_w    = (const float*)d_in[8];
    const float* fc1_b    = (const float*)d_in[9];
    const float* fc2_w    = (const float*)d_in[10];
    const float* fc2_b    = (const float*)d_in[11];
    const float* fc3_w    = (const float*)d_in[12];
    const float* fc3_b    = (const float*)d_in[13];

    // ws: pooled bf16 (46.1MB) | w1 bf16 (23.1MB) | partial f32 (8.4MB) | glvl8 (16.8MB)
    unsigned short* pooledb = (unsigned short*)d_ws;
    unsigned short* w1b     = pooledb + (long)BATCH * FDIM;
    float*          partial = (float*)(w1b + (long)H1 * FDIM);
    float*          glvl8   = partial + (long)KS * BATCH * H1;

    w1_convert<<<1024, 256, 0, stream>>>(fc1_w, w1b);

    tree08<<<BATCH * 2, 256, 0, stream>>>(
        x, leaf_w, leaf_b, conv_w, conv_b, bn_gamma, bn_beta, node_w, pooledb, glvl8);

    tree9<<<BATCH, 512, 0, stream>>>(glvl8, conv_w, conv_b, bn_gamma, bn_beta,
                                     node_w, pooledb);

    fc1_mfma<<<512, 256, 0, stream>>>(pooledb, w1b, partial);

    fc_tail<<<BATCH, 128, 0, stream>>>(partial, fc1_b, fc2_w, fc2_b, fc3_w, fc3_b,
                                       (float*)d_out, KS);
}

// Round 18
// 134.857 us; speedup vs baseline: 1.6910x; 1.6910x over previous
//
#include <hip/hip_runtime.h>

#define BATCH 256
#define L 1024
#define C 16
#define POOL 512
#define PCOLS 5632
#define FDIM 90112        // C*PCOLS
#define H1 128
#define H2 64

#define KS 64             // split-K factor for fc1 mfma GEMM
#define KCHUNK (FDIM / KS)   // 1408

#define SROW 24                    // bf16 per state row (48B, 16B-aligned, ~2-way banks)
#define SBUF (1025 * SROW)         // +1 zero row
#define TREE_LDS_BYTES (2 * SBUF * 2)   // 98400 B -> 1 block/CU

typedef float f32x4 __attribute__((ext_vector_type(4)));
typedef short bf16x8 __attribute__((ext_vector_type(8)));

__device__ __forceinline__ unsigned short f2b(float f) {
    union { float f; unsigned int u; } v; v.f = f;
    unsigned int r = (v.u + 0x7FFFu + ((v.u >> 16) & 1u)) >> 16;   // RNE
    return (unsigned short)r;
}
__device__ __forceinline__ unsigned int pk(float lo, float hi) {
    return (unsigned int)f2b(lo) | ((unsigned int)f2b(hi) << 16);
}

// ---------------- Kernel 1: tree via MFMA ----------------
// State bf16 in LDS [pos][ci] stride SROW, double-buffered. Per level each wave
// computes 8 16-pos tiles: D[co][pos] = W*window via 2x mfma_f32_16x16x32_bf16.
__launch_bounds__(512, 1)
__global__ void tree_kernel(const float* __restrict__ x,
                            const float* __restrict__ leaf_w,
                            const float* __restrict__ leaf_b,
                            const float* __restrict__ conv_w,
                            const float* __restrict__ conv_b,
                            const float* __restrict__ bn_gamma,
                            const float* __restrict__ bn_beta,
                            const float* __restrict__ node_w,
                            unsigned short* __restrict__ pooledb) {
    extern __shared__ short smem[];
    short* buf0 = smem;
    short* buf1 = smem + SBUF;

    const int b   = blockIdx.x;
    const int tid = threadIdx.x;
    const int lane = tid & 63;
    const int wv   = tid >> 6;          // 8 waves
    const int n    = lane & 15;         // position-in-tile / A-B source row
    const int g    = lane >> 4;         // k-group

    // zero rows (row 1024 of both buffers) for boundary redirect
    for (int i = tid; i < SROW; i += 512) {
        buf0[1024 * SROW + i] = 0;
        buf1[1024 * SROW + i] = 0;
    }

    // ---- preload A fragments (weights, bf16) and epilogue constants ----
    // A1: k=8g+j -> tap=g>>1, ci=(g&1)*8+j ; A2: k<16 -> tap2, ci=k (g<2), else 0
    bf16x8 A1, A2;
#pragma unroll
    for (int j = 0; j < 8; ++j) {
        const int ci = (g & 1) * 8 + j;
        A1[j] = (short)f2b(conv_w[((lane & 15) * C + ci) * 3 + (g >> 1)]);
        A2[j] = (g < 2) ? (short)f2b(conv_w[((lane & 15) * C + ci) * 3 + 2]) : (short)0;
    }
    float sc4[4], bt4[4];
#pragma unroll
    for (int r = 0; r < 4; ++r) {
        const int co = g * 4 + r;       // D-row set for this lane
        float s = bn_gamma[co] / sqrtf(1.0f + 1e-5f);
        sc4[r] = s;
        bt4[r] = conv_b[co] * s + bn_beta[co];
    }

    // ---- leaf stage: thread owns positions (2tid, 2tid+1) ----
    {
        const float2 xv  = *(const float2*)(x + b * L + 2 * tid);
        const float2 nw2 = *(const float2*)(node_w + 2 * tid);
        const float4* lwa = (const float4*)(leaf_w + 32 * tid);
        const float4* lba = (const float4*)(leaf_b + 32 * tid);
        unsigned int* row0 = (unsigned int*)(buf0 + (2 * tid) * SROW);
        unsigned int* row1 = (unsigned int*)(buf0 + (2 * tid + 1) * SROW);
#pragma unroll 1
        for (int q = 0; q < 4; ++q) {
            float4 w0 = lwa[q],     bb0 = lba[q];
            float4 w1 = lwa[q + 4], bb1 = lba[q + 4];
            float v0[4], v1[4];
            v0[0] = (xv.x * w0.x + bb0.x) * nw2.x;  v1[0] = (xv.y * w1.x + bb1.x) * nw2.y;
            v0[1] = (xv.x * w0.y + bb0.y) * nw2.x;  v1[1] = (xv.y * w1.y + bb1.y) * nw2.y;
            v0[2] = (xv.x * w0.z + bb0.z) * nw2.x;  v1[2] = (xv.y * w1.z + bb1.z) * nw2.y;
            v0[3] = (xv.x * w0.w + bb0.w) * nw2.x;  v1[3] = (xv.y * w1.w + bb1.w) * nw2.y;
            row0[2 * q]     = pk(v0[0], v0[1]);
            row0[2 * q + 1] = pk(v0[2], v0[3]);
            row1[2 * q]     = pk(v1[0], v1[1]);
            row1[2 * q + 1] = pk(v1[2], v1[3]);
#pragma unroll
            for (int j = 0; j < 4; ++j) {
                int c = 4 * q + j;
                pooledb[b * FDIM + c * PCOLS + tid] = f2b(fmaxf(v0[j], v1[j]));
            }
        }
        __syncthreads();
    }

    // ---- 10 levels via MFMA ----
    short* bin  = buf0;
    short* bout = buf1;
    int noff = L;
    for (int d = 0; d < 10; ++d) {
        const int sh = d + 1;
        const int mask = (1 << sh) - 1;          // L2-1

#pragma unroll 1
        for (int ti = 0; ti < 8; ++ti) {
            const int pos = (wv * 8 + ti) * 16 + n;
            // B1: rows pos + (g>>1) - 1 (taps 0/1); tap0 lanes zero at node start
            const bool ok1 = (g >= 2) || ((pos & mask) != 0);
            const int r1 = ok1 ? (pos + (g >> 1) - 1) : 1024;
            bf16x8 B1 = *(const bf16x8*)(bin + r1 * SROW + (g & 1) * 8);
            // B2: row pos+1 (tap 2); zero at node end
            const bool ok2 = ((pos & mask) != mask);
            const int r2 = ok2 ? (pos + 1) : 1024;
            bf16x8 B2 = *(const bf16x8*)(bin + r2 * SROW + (g & 1) * 8);

            f32x4 acc = {0.f, 0.f, 0.f, 0.f};
            acc = __builtin_amdgcn_mfma_f32_16x16x32_bf16(A1, B1, acc, 0, 0, 0);
            acc = __builtin_amdgcn_mfma_f32_16x16x32_bf16(A2, B2, acc, 0, 0, 0);

            const float nwv = node_w[noff + (pos >> sh)];
            float z[4];
#pragma unroll
            for (int r = 0; r < 4; ++r)
                z[r] = fmaxf(fmaf(sc4[r], acc[r], bt4[r]), 0.f) * nwv;

            // state write: row pos, ci group g*4 (2x u32 = b64)
            unsigned int* sw = (unsigned int*)(bout + pos * SROW + g * 4);
            sw[0] = pk(z[0], z[1]);
            sw[1] = pk(z[2], z[3]);

            // pooling: pair (pos even, pos odd) via lane xor 1
#pragma unroll
            for (int r = 0; r < 4; ++r) {
                float pz = fmaxf(z[r], __shfl_xor(z[r], 1));
                if (!(n & 1))
                    pooledb[b * FDIM + (g * 4 + r) * PCOLS + sh * POOL + (pos >> 1)] =
                        f2b(pz);
            }
        }

        __syncthreads();
        short* t = bin; bin = bout; bout = t;
        noff += (512 >> d);
    }
}

// ---------------- Kernel 1b: fc1_w f32 -> bf16 ----------------
__launch_bounds__(256)
__global__ void w1_convert(const float* __restrict__ w1,
                           unsigned short* __restrict__ w1b) {
    const int n4 = (H1 * FDIM) >> 2;
    for (int i = blockIdx.x * blockDim.x + threadIdx.x; i < n4;
         i += gridDim.x * blockDim.x) {
        float4 v = *(const float4*)(w1 + 4 * i);
        ushort4 o;
        o.x = f2b(v.x); o.y = f2b(v.y); o.z = f2b(v.z); o.w = f2b(v.w);
        *(ushort4*)(w1b + 4 * i) = o;
    }
}

// ---------------- Kernel 2: fc1 via MFMA bf16, split-K, no LDS ----------------
__launch_bounds__(256, 2)
__global__ void fc1_mfma(const unsigned short* __restrict__ pooledb,
                         const unsigned short* __restrict__ w1b,
                         float* __restrict__ partial) {
    const int bid = blockIdx.x;
    const int ks  = bid & (KS - 1);
    const int g   = bid >> 6;
    const int bm  = g >> 1;
    const int bn  = g & 1;

    const int tid  = threadIdx.x;
    const int wv   = tid >> 6;
    const int lane = tid & 63;

    const int m0 = bm * 64 + wv * 16;
    const int n0 = bn * 64;
    const int kb = ks * KCHUNK;

    const unsigned short* ap  = pooledb + (long)(m0 + (lane & 15)) * FDIM + kb + (lane >> 4) * 8;
    const unsigned short* bp0 = w1b + (long)(n0 + (lane & 15)) * FDIM + kb + (lane >> 4) * 8;

    f32x4 acc0 = {0.f, 0.f, 0.f, 0.f};
    f32x4 acc1 = {0.f, 0.f, 0.f, 0.f};
    f32x4 acc2 = {0.f, 0.f, 0.f, 0.f};
    f32x4 acc3 = {0.f, 0.f, 0.f, 0.f};

#pragma unroll 2
    for (int kk = 0; kk < KCHUNK; kk += 32) {
        bf16x8 a  = *(const bf16x8*)(ap + kk);
        bf16x8 b0 = *(const bf16x8*)(bp0 + kk);
        bf16x8 b1 = *(const bf16x8*)(bp0 + 16 * FDIM + kk);
        bf16x8 b2 = *(const bf16x8*)(bp0 + 32 * FDIM + kk);
        bf16x8 b3 = *(const bf16x8*)(bp0 + 48 * FDIM + kk);
        acc0 = __builtin_amdgcn_mfma_f32_16x16x32_bf16(a, b0, acc0, 0, 0, 0);
        acc1 = __builtin_amdgcn_mfma_f32_16x16x32_bf16(a, b1, acc1, 0, 0, 0);
        acc2 = __builtin_amdgcn_mfma_f32_16x16x32_bf16(a, b2, acc2, 0, 0, 0);
        acc3 = __builtin_amdgcn_mfma_f32_16x16x32_bf16(a, b3, acc3, 0, 0, 0);
    }

    const int crow = m0 + (lane >> 4) * 4;
    const int ccol = n0 + (lane & 15);
    float* pp = partial + (long)ks * (BATCH * H1) + (long)crow * H1 + ccol;
#pragma unroll
    for (int r = 0; r < 4; ++r) {
        pp[(long)r * H1]      = acc0[r];
        pp[(long)r * H1 + 16] = acc1[r];
        pp[(long)r * H1 + 32] = acc2[r];
        pp[(long)r * H1 + 48] = acc3[r];
    }
}

// ---------------- Kernel 3: reduce partials + fc1 bias/relu + fc2 + fc3 ----------
__launch_bounds__(128)
__global__ void fc_tail(const float* __restrict__ partial,
                        const float* __restrict__ fc1_b,
                        const float* __restrict__ w2,
                        const float* __restrict__ b2,
                        const float* __restrict__ w3,
                        const float* __restrict__ b3,
                        float* __restrict__ out, int nkt) {
    __shared__ float h1_s[H1];
    __shared__ float w2_s[H2 * 129];

    const int b = blockIdx.x;
    const int t = threadIdx.x;

    float s = 0.f;
    for (int kt = 0; kt < nkt; ++kt)
        s += partial[(long)kt * (BATCH * H1) + b * H1 + t];
    h1_s[t] = fmaxf(s + fc1_b[t], 0.f);

    for (int i = t; i < H2 * H1; i += 128) {
        int j = i >> 7, k = i & 127;
        w2_s[j * 129 + k] = w2[i];
    }
    __syncthreads();

    if (t < 64) {
        float a2 = 0.f;
#pragma unroll 8
        for (int k = 0; k < H1; ++k) a2 = fmaf(h1_s[k], w2_s[t * 129 + k], a2);
        float h2 = fmaxf(a2 + b2[t], 0.f);
        float r = h2 * w3[t];
#pragma unroll
        for (int off = 32; off > 0; off >>= 1) r += __shfl_down(r, off);
        if (t == 0) out[b] = r + b3[0];
    }
}

extern "C" void kernel_launch(void* const* d_in, const int* in_sizes, int n_in,
                              void* d_out, int out_size, void* d_ws, size_t ws_size,
                              hipStream_t stream) {
    const float* x        = (const float*)d_in[0];
    const float* leaf_w   = (const float*)d_in[1];
    const float* leaf_b   = (const float*)d_in[2];
    const float* conv_w   = (const float*)d_in[3];
    const float* conv_b   = (const float*)d_in[4];
    const float* bn_gamma = (const float*)d_in[5];
    const float* bn_beta  = (const float*)d_in[6];
    const float* node_w   = (const float*)d_in[7];
    const float* fc1_w    = (const float*)d_in[8];
    const float* fc1_b    = (const float*)d_in[9];
    const float* fc2_w    = (const float*)d_in[10];
    const float* fc2_b    = (const float*)d_in[11];
    const float* fc3_w    = (const float*)d_in[12];
    const float* fc3_b    = (const float*)d_in[13];

    // ws: pooled bf16 (46.1MB) | w1 bf16 (23.1MB) | partial f32 (8.4MB)
    unsigned short* pooledb = (unsigned short*)d_ws;
    unsigned short* w1b     = pooledb + (long)BATCH * FDIM;
    float*          partial = (float*)(w1b + (long)H1 * FDIM);

    (void)hipFuncSetAttribute((const void*)tree_kernel,
                        hipFuncAttributeMaxDynamicSharedMemorySize, TREE_LDS_BYTES);

    w1_convert<<<1024, 256, 0, stream>>>(fc1_w, w1b);

    tree_kernel<<<BATCH, 512, TREE_LDS_BYTES, stream>>>(
        x, leaf_w, leaf_b, conv_w, conv_b, bn_gamma, bn_beta, node_w, pooledb);

    fc1_mfma<<<512, 256, 0, stream>>>(pooledb, w1b, partial);

    fc_tail<<<BATCH, 128, 0, stream>>>(partial, fc1_b, fc2_w, fc2_b, fc3_w, fc3_b,
                                       (float*)d_out, KS);
}

// Round 19
// 134.466 us; speedup vs baseline: 1.6959x; 1.0029x over previous
//
#include <hip/hip_runtime.h>

#define BATCH 256
#define L 1024
#define C 16
#define POOL 512
#define PCOLS 5632
#define FDIM 90112        // C*PCOLS
#define H1 128
#define H2 64

#define KS 64             // split-K factor for fc1 mfma GEMM
#define KCHUNK (FDIM / KS)   // 1408

#define SROW 24                    // bf16 per state row (48B, 16B-aligned)
#define SBUF (1025 * SROW)         // +1 zero row
#define TREE_LDS_BYTES (2 * SBUF * 2)   // 98400 B

typedef float f32x4 __attribute__((ext_vector_type(4)));
typedef short bf16x8 __attribute__((ext_vector_type(8)));

__device__ __forceinline__ unsigned short f2b(float f) {
    union { float f; unsigned int u; } v; v.f = f;
    unsigned int r = (v.u + 0x7FFFu + ((v.u >> 16) & 1u)) >> 16;   // RNE
    return (unsigned short)r;
}
__device__ __forceinline__ unsigned int pk(float lo, float hi) {
    return (unsigned int)f2b(lo) | ((unsigned int)f2b(hi) << 16);
}

// ---------------- Kernel 1: tree via MFMA, 1024 threads (16 waves/CU) ----------------
__launch_bounds__(1024, 4)
__global__ void tree_kernel(const float* __restrict__ x,
                            const float* __restrict__ leaf_w,
                            const float* __restrict__ leaf_b,
                            const float* __restrict__ conv_w,
                            const float* __restrict__ conv_b,
                            const float* __restrict__ bn_gamma,
                            const float* __restrict__ bn_beta,
                            const float* __restrict__ node_w,
                            unsigned short* __restrict__ pooledb) {
    extern __shared__ short smem[];
    short* buf0 = smem;
    short* buf1 = smem + SBUF;

    const int b   = blockIdx.x;
    const int tid = threadIdx.x;          // 0..1023
    const int lane = tid & 63;
    const int wv   = tid >> 6;            // 16 waves
    const int n    = lane & 15;
    const int g    = lane >> 4;

    // zero rows (row 1024) for boundary redirect
    if (tid < SROW) {
        buf0[1024 * SROW + tid] = 0;
        buf1[1024 * SROW + tid] = 0;
    }

    // ---- preload A fragments (weights) and epilogue constants ----
    bf16x8 A1, A2;
#pragma unroll
    for (int j = 0; j < 8; ++j) {
        const int ci = (g & 1) * 8 + j;
        A1[j] = (short)f2b(conv_w[(n * C + ci) * 3 + (g >> 1)]);
        A2[j] = (g < 2) ? (short)f2b(conv_w[(n * C + ci) * 3 + 2]) : (short)0;
    }
    float sc4[4], bt4[4];
#pragma unroll
    for (int r = 0; r < 4; ++r) {
        const int co = g * 4 + r;
        float s = bn_gamma[co] / sqrtf(1.0f + 1e-5f);
        sc4[r] = s;
        bt4[r] = conv_b[co] * s + bn_beta[co];
    }

    // ---- leaf stage: 1 position per thread ----
    {
        const float xv = x[b * L + tid];
        const float nw = node_w[tid];
        const float4* lwa = (const float4*)(leaf_w + 16 * tid);
        const float4* lba = (const float4*)(leaf_b + 16 * tid);
        unsigned int* row = (unsigned int*)(buf0 + tid * SROW);
        const int pb0 = b * FDIM + (tid >> 1);
#pragma unroll 1
        for (int q = 0; q < 4; ++q) {
            float4 wq = lwa[q], bq = lba[q];
            float v0 = (xv * wq.x + bq.x) * nw;
            float v1 = (xv * wq.y + bq.y) * nw;
            float v2 = (xv * wq.z + bq.z) * nw;
            float v3 = (xv * wq.w + bq.w) * nw;
            row[2 * q]     = pk(v0, v1);
            row[2 * q + 1] = pk(v2, v3);
            float p0 = fmaxf(v0, __shfl_xor(v0, 1));
            float p1 = fmaxf(v1, __shfl_xor(v1, 1));
            float p2 = fmaxf(v2, __shfl_xor(v2, 1));
            float p3 = fmaxf(v3, __shfl_xor(v3, 1));
            if (!(tid & 1)) {
                const int c = 4 * q;
                pooledb[pb0 + (c + 0) * PCOLS] = f2b(p0);
                pooledb[pb0 + (c + 1) * PCOLS] = f2b(p1);
                pooledb[pb0 + (c + 2) * PCOLS] = f2b(p2);
                pooledb[pb0 + (c + 3) * PCOLS] = f2b(p3);
            }
        }
        __syncthreads();
    }

    // ---- 10 levels via MFMA: 4 tiles per wave ----
    short* bin  = buf0;
    short* bout = buf1;
    int noff = L;
    for (int d = 0; d < 10; ++d) {
        const int sh = d + 1;
        const int mask = (1 << sh) - 1;

#pragma unroll 1
        for (int ti = 0; ti < 4; ++ti) {
            const int pos = (wv * 4 + ti) * 16 + n;
            const bool ok1 = (g >= 2) || ((pos & mask) != 0);
            const int r1 = ok1 ? (pos + (g >> 1) - 1) : 1024;
            bf16x8 B1 = *(const bf16x8*)(bin + r1 * SROW + (g & 1) * 8);
            const bool ok2 = ((pos & mask) != mask);
            const int r2 = ok2 ? (pos + 1) : 1024;
            bf16x8 B2 = *(const bf16x8*)(bin + r2 * SROW + (g & 1) * 8);

            f32x4 acc = {0.f, 0.f, 0.f, 0.f};
            acc = __builtin_amdgcn_mfma_f32_16x16x32_bf16(A1, B1, acc, 0, 0, 0);
            acc = __builtin_amdgcn_mfma_f32_16x16x32_bf16(A2, B2, acc, 0, 0, 0);

            const float nwv = node_w[noff + (pos >> sh)];
            float z[4];
#pragma unroll
            for (int r = 0; r < 4; ++r)
                z[r] = fmaxf(fmaf(sc4[r], acc[r], bt4[r]), 0.f) * nwv;

            unsigned int* sw = (unsigned int*)(bout + pos * SROW + g * 4);
            sw[0] = pk(z[0], z[1]);
            sw[1] = pk(z[2], z[3]);

#pragma unroll
            for (int r = 0; r < 4; ++r) {
                float pz = fmaxf(z[r], __shfl_xor(z[r], 1));
                if (!(n & 1))
                    pooledb[b * FDIM + (g * 4 + r) * PCOLS + sh * POOL + (pos >> 1)] =
                        f2b(pz);
            }
        }

        __syncthreads();
        short* t = bin; bin = bout; bout = t;
        noff += (512 >> d);
    }
}

// ---------------- Kernel 1b: fc1_w f32 -> bf16 ----------------
__launch_bounds__(256)
__global__ void w1_convert(const float* __restrict__ w1,
                           unsigned short* __restrict__ w1b) {
    const int n4 = (H1 * FDIM) >> 2;
    for (int i = blockIdx.x * blockDim.x + threadIdx.x; i < n4;
         i += gridDim.x * blockDim.x) {
        float4 v = *(const float4*)(w1 + 4 * i);
        ushort4 o;
        o.x = f2b(v.x); o.y = f2b(v.y); o.z = f2b(v.z); o.w = f2b(v.w);
        *(ushort4*)(w1b + 4 * i) = o;
    }
}

// ---------------- Kernel 2: fc1 via MFMA bf16, split-K, no LDS ----------------
__launch_bounds__(256, 2)
__global__ void fc1_mfma(const unsigned short* __restrict__ pooledb,
                         const unsigned short* __restrict__ w1b,
                         float* __restrict__ partial) {
    const int bid = blockIdx.x;
    const int ks  = bid & (KS - 1);
    const int g   = bid >> 6;
    const int bm  = g >> 1;
    const int bn  = g & 1;

    const int tid  = threadIdx.x;
    const int wv   = tid >> 6;
    const int lane = tid & 63;

    const int m0 = bm * 64 + wv * 16;
    const int n0 = bn * 64;
    const int kb = ks * KCHUNK;

    const unsigned short* ap  = pooledb + (long)(m0 + (lane & 15)) * FDIM + kb + (lane >> 4) * 8;
    const unsigned short* bp0 = w1b + (long)(n0 + (lane & 15)) * FDIM + kb + (lane >> 4) * 8;

    f32x4 acc0 = {0.f, 0.f, 0.f, 0.f};
    f32x4 acc1 = {0.f, 0.f, 0.f, 0.f};
    f32x4 acc2 = {0.f, 0.f, 0.f, 0.f};
    f32x4 acc3 = {0.f, 0.f, 0.f, 0.f};

#pragma unroll 4
    for (int kk = 0; kk < KCHUNK; kk += 32) {
        bf16x8 a  = *(const bf16x8*)(ap + kk);
        bf16x8 b0 = *(const bf16x8*)(bp0 + kk);
        bf16x8 b1 = *(const bf16x8*)(bp0 + 16 * FDIM + kk);
        bf16x8 b2 = *(const bf16x8*)(bp0 + 32 * FDIM + kk);
        bf16x8 b3 = *(const bf16x8*)(bp0 + 48 * FDIM + kk);
        acc0 = __builtin_amdgcn_mfma_f32_16x16x32_bf16(a, b0, acc0, 0, 0, 0);
        acc1 = __builtin_amdgcn_mfma_f32_16x16x32_bf16(a, b1, acc1, 0, 0, 0);
        acc2 = __builtin_amdgcn_mfma_f32_16x16x32_bf16(a, b2, acc2, 0, 0, 0);
        acc3 = __builtin_amdgcn_mfma_f32_16x16x32_bf16(a, b3, acc3, 0, 0, 0);
    }

    const int crow = m0 + (lane >> 4) * 4;
    const int ccol = n0 + (lane & 15);
    float* pp = partial + (long)ks * (BATCH * H1) + (long)crow * H1 + ccol;
#pragma unroll
    for (int r = 0; r < 4; ++r) {
        pp[(long)r * H1]      = acc0[r];
        pp[(long)r * H1 + 16] = acc1[r];
        pp[(long)r * H1 + 32] = acc2[r];
        pp[(long)r * H1 + 48] = acc3[r];
    }
}

// ---------------- Kernel 3: reduce partials + fc1 bias/relu + fc2 + fc3 ----------
__launch_bounds__(128)
__global__ void fc_tail(const float* __restrict__ partial,
                        const float* __restrict__ fc1_b,
                        const float* __restrict__ w2,
                        const float* __restrict__ b2,
                        const float* __restrict__ w3,
                        const float* __restrict__ b3,
                        float* __restrict__ out, int nkt) {
    __shared__ float h1_s[H1];
    __shared__ float w2_s[H2 * 129];

    const int b = blockIdx.x;
    const int t = threadIdx.x;

    float s = 0.f;
    for (int kt = 0; kt < nkt; ++kt)
        s += partial[(long)kt * (BATCH * H1) + b * H1 + t];
    h1_s[t] = fmaxf(s + fc1_b[t], 0.f);

    for (int i = t; i < H2 * H1; i += 128) {
        int j = i >> 7, k = i & 127;
        w2_s[j * 129 + k] = w2[i];
    }
    __syncthreads();

    if (t < 64) {
        float a2 = 0.f;
#pragma unroll 8
        for (int k = 0; k < H1; ++k) a2 = fmaf(h1_s[k], w2_s[t * 129 + k], a2);
        float h2 = fmaxf(a2 + b2[t], 0.f);
        float r = h2 * w3[t];
#pragma unroll
        for (int off = 32; off > 0; off >>= 1) r += __shfl_down(r, off);
        if (t == 0) out[b] = r + b3[0];
    }
}

extern "C" void kernel_launch(void* const* d_in, const int* in_sizes, int n_in,
                              void* d_out, int out_size, void* d_ws, size_t ws_size,
                              hipStream_t stream) {
    const float* x        = (const float*)d_in[0];
    const float* leaf_w   = (const float*)d_in[1];
    const float* leaf_b   = (const float*)d_in[2];
    const float* conv_w   = (const float*)d_in[3];
    const float* conv_b   = (const float*)d_in[4];
    const float* bn_gamma = (const float*)d_in[5];
    const float* bn_beta  = (const float*)d_in[6];
    const float* node_w   = (const float*)d_in[7];
    const float* fc1_w    = (const float*)d_in[8];
    const float* fc1_b    = (const float*)d_in[9];
    const float* fc2_w    = (const float*)d_in[10];
    const float* fc2_b    = (const float*)d_in[11];
    const float* fc3_w    = (const float*)d_in[12];
    const float* fc3_b    = (const float*)d_in[13];

    // ws: pooled bf16 (46.1MB) | w1 bf16 (23.1MB) | partial f32 (8.4MB)
    unsigned short* pooledb = (unsigned short*)d_ws;
    unsigned short* w1b     = pooledb + (long)BATCH * FDIM;
    float*          partial = (float*)(w1b + (long)H1 * FDIM);

    (void)hipFuncSetAttribute((const void*)tree_kernel,
                        hipFuncAttributeMaxDynamicSharedMemorySize, TREE_LDS_BYTES);

    w1_convert<<<1024, 256, 0, stream>>>(fc1_w, w1b);

    tree_kernel<<<BATCH, 1024, TREE_LDS_BYTES, stream>>>(
        x, leaf_w, leaf_b, conv_w, conv_b, bn_gamma, bn_beta, node_w, pooledb);

    fc1_mfma<<<512, 256, 0, stream>>>(pooledb, w1b, partial);

    fc_tail<<<BATCH, 128, 0, stream>>>(partial, fc1_b, fc2_w, fc2_b, fc3_w, fc3_b,
                                       (float*)d_out, KS);
}